// Round 11
// baseline (227.828 us; speedup 1.0000x reference)
//
#include <hip/hip_runtime.h>
#include <hip/hip_bf16.h>
#include <stdint.h>

#define DEVI __device__ __forceinline__

typedef __bf16 bf16x8 __attribute__((ext_vector_type(8)));
typedef float f32x4 __attribute__((ext_vector_type(4)));
typedef unsigned short ushort8v __attribute__((ext_vector_type(8)));

static constexpr int SEQ = 4096;
static constexpr int DIM_ = 1024;
static constexpr int NH = 16;
static constexpr int HD_ = 64;
static constexpr float SCALE_ = 0.125f;  // 1/sqrt(64)

DEVI unsigned short f2bf(float f) {
  __hip_bfloat16 h = __float2bfloat16(f);
  return __builtin_bit_cast(unsigned short, h);
}

// ---------------------------------------------------------------- conversions

__global__ void k_cvt_bf16(const float* __restrict__ in, unsigned short* __restrict__ out) {
  int i = (blockIdx.x * 256 + threadIdx.x) * 4;
  float4 v = *reinterpret_cast<const float4*>(in + i);
  ushort4 o;
  o.x = f2bf(v.x); o.y = f2bf(v.y); o.z = f2bf(v.z); o.w = f2bf(v.w);
  *reinterpret_cast<ushort4*>(out + i) = o;
}

// in: K x N f32 (row-major), out: N x K bf16 (row-major)
__global__ void k_transpose_cvt(const float* __restrict__ in, unsigned short* __restrict__ out,
                                int K, int N) {
  __shared__ float tile[64][65];
  const int n0 = blockIdx.x * 64, k0 = blockIdx.y * 64;
  const int tr = threadIdx.x >> 6, tc = threadIdx.x & 63;
#pragma unroll
  for (int p = 0; p < 16; ++p) {
    int r = p * 4 + tr;
    tile[r][tc] = in[(size_t)(k0 + r) * N + n0 + tc];
  }
  __syncthreads();
#pragma unroll
  for (int p = 0; p < 16; ++p) {
    int r = p * 4 + tr;  // output row (n index)
    out[(size_t)(n0 + r) * K + k0 + tc] = f2bf(tile[tc][r]);
  }
}

// ---------------------------------------------------------------- GEMM (A: MxK bf16, Bt: NxK bf16)
// LDS-traffic-reduction design (r10 theory: 128x128 all-LDS structure is LDS-BW-bound at
// 48 B/KFLOP; four pipeline variants all plateaued at ~70us/735TF):
//   - BK=64; A staged in LDS (gload_lds, T2 chunk-XOR swizzle, 2 buffers, ONE barrier/tile)
//   - B NEVER touches LDS: per-wave fragments double-buffered in REGISTERS, loaded from
//     global (B panel hot in L1/L2) 1-2 tiles ahead
//   - counted vmcnt only: vmcnt(4) retires next B bank (keeps A's 4 staged loads in
//     flight); vmcnt(8) retires A(t+1) (keeps B(t+2)'s 8 in flight). Never drains to 0.
//   LDS per block-tile: A reads 32KB + writes 16KB per 2M FLOP = 24 B/KFLOP (was 48).
// MODE 0: outF[row*N+col] = acc + bias[col]  (f32)
// MODE 1: qkv scatter -> outQ/outK/outV bf16, layout [b][h][s][d]

DEVI void load16_lds(const void* g, void* l) {
  __builtin_amdgcn_global_load_lds((__attribute__((address_space(1))) void*)(g),
                                   (__attribute__((address_space(3))) void*)(l),
                                   16, 0, 0);
}

template <int MODE>
__global__ __launch_bounds__(256, 2)
void k_gemm_bt(const unsigned short* __restrict__ A,
               const unsigned short* __restrict__ Bt,
               const float* __restrict__ bias,
               float* __restrict__ outF,
               unsigned short* __restrict__ outQ,
               unsigned short* __restrict__ outK,
               unsigned short* __restrict__ outV,
               int M, int N, int K) {
  constexpr int BK = 64;
  __shared__ alignas(16) unsigned short As[2][128 * BK];  // 2 x 16 KB
  const int tid = threadIdx.x;
  const int wave = tid >> 6, lane = tid & 63;
  const int wr = wave >> 1, wc = wave & 1;
  const int l15 = lane & 15, q = lane >> 4;
  const int bm = blockIdx.x * 128, bn = blockIdx.y * 128;
  const int NT = K >> 6;  // even (K=1024 -> 16)

  f32x4 acc[4][4] = {};

  // ---- A staging (per wave: 4 x gload_lds of 1KB = rows wave*32..wave*32+31)
  // lane -> row = base + (lane>>3), slot chunk = lane&7; logical chunk = slot ^ ((row>>1)&7)
  const int srow0 = wave * 32 + (lane >> 3);
  const int srow1 = srow0 + 8;
  const int ca0 = (lane & 7) ^ ((srow0 >> 1) & 7);
  const int ca1 = (lane & 7) ^ ((srow1 >> 1) & 7);
  const unsigned short* aP0 = A + (size_t)(bm + srow0) * K + ca0 * 8;
  const unsigned short* aP1 = A + (size_t)(bm + srow1) * K + ca1 * 8;
  const size_t K16 = (size_t)16 * K;

#define STAGEA(T, BUF)                                                  \
  {                                                                     \
    const int kk = (T) * 64;                                            \
    load16_lds(aP0 + kk, &As[BUF][(wave * 32 + 0) * 64]);               \
    load16_lds(aP1 + kk, &As[BUF][(wave * 32 + 8) * 64]);               \
    load16_lds(aP0 + K16 + kk, &As[BUF][(wave * 32 + 16) * 64]);        \
    load16_lds(aP1 + K16 + kk, &As[BUF][(wave * 32 + 24) * 64]);        \
  }

  // ---- B fragment loads (global -> regs): lane (q,l15) of frag (n,ks) reads
  // Bt[(bn + wc*64 + n*16 + l15)][t*64 + ks*32 + q*8 .. +7]  (16B, L1/L2-hot panel)
  const unsigned short* bGB = Bt + (size_t)(bn + wc * 64 + l15) * K + q * 8;

#define LOADB(BANK, T)                                                  \
  {                                                                     \
    const int kk = (T) * 64;                                            \
    _Pragma("unroll") for (int n = 0; n < 4; ++n) {                     \
      BANK[0][n] = *reinterpret_cast<const bf16x8*>(bGB + (size_t)n * K16 + kk);      \
      BANK[1][n] = *reinterpret_cast<const bf16x8*>(bGB + (size_t)n * K16 + kk + 32); \
    }                                                                   \
  }

  // ---- A read offsets: row = wr*64 + m*16 + l15; logical chunk c = ks*4+q stored at
  // slot c ^ x7, x7 = (row>>1)&7 = (l15>>1)&7 (wr*64, m*16 contribute 0 mod 8)
  const int x7 = (l15 >> 1) & 7;

#define TILE_BODY(T, BUF, BCUR)                                          \
  {                                                                      \
    const int tn = ((T) + 1 < NT) ? (T) + 1 : NT - 1;                    \
    const int tb = ((T) + 2 < NT) ? (T) + 2 : NT - 1;                    \
    STAGEA(tn, BUF ^ 1);                                                 \
    _Pragma("unroll") for (int ks = 0; ks < 2; ++ks) {                   \
      bf16x8 af[4];                                                      \
      _Pragma("unroll") for (int m = 0; m < 4; ++m)                      \
        af[m] = *reinterpret_cast<const bf16x8*>(                        \
            &As[BUF][(wr * 64 + m * 16 + l15) * 64 + ((ks * 4 + q) ^ x7) * 8]); \
      _Pragma("unroll") for (int m = 0; m < 4; ++m)                      \
        _Pragma("unroll") for (int n = 0; n < 4; ++n)                    \
          acc[m][n] = __builtin_amdgcn_mfma_f32_16x16x32_bf16(           \
              af[m], BCUR[ks][n], acc[m][n], 0, 0, 0);                   \
    }                                                                    \
    asm volatile("s_waitcnt vmcnt(4)" ::: "memory");                     \
    LOADB(BCUR, tb);                                                     \
    asm volatile("s_waitcnt vmcnt(8)" ::: "memory");                     \
    __builtin_amdgcn_s_barrier();                                        \
  }

  bf16x8 bA[2][4], bB[2][4];
  // prologue: B(0) -> bA (8), stage A(0) (4), B(1) -> bB (8); retire first 12 -> vmcnt(8)
  LOADB(bA, 0);
  STAGEA(0, 0);
  LOADB(bB, 1);
  asm volatile("s_waitcnt vmcnt(8)" ::: "memory");
  __builtin_amdgcn_s_barrier();

#pragma unroll 1
  for (int t = 0; t < NT; t += 2) {
    TILE_BODY(t, 0, bA);
    TILE_BODY(t + 1, 1, bB);
  }
#undef TILE_BODY
#undef LOADB
#undef STAGEA

  // epilogue: D frag (16x16) mapping col = lane&15, row = (lane>>4)*4 + j
  const int r0 = q * 4;
#pragma unroll
  for (int m = 0; m < 4; ++m) {
#pragma unroll
    for (int n = 0; n < 4; ++n) {
      const int col = bn + wc * 64 + n * 16 + l15;
      const float bv = bias[col];
#pragma unroll
      for (int j = 0; j < 4; ++j) {
        const int row = bm + wr * 64 + m * 16 + r0 + j;
        const float v = acc[m][n][j] + bv;
        if constexpr (MODE == 0) {
          outF[(size_t)row * N + col] = v;
        } else {
          const int t = col >> 10;          // 0:Q 1:K 2:V
          const int hh = (col >> 6) & 15;   // head
          const int d = col & 63;
          const int b = row >> 12;
          const int s = row & 4095;
          unsigned short* dst = (t == 0) ? outQ : (t == 1) ? outK : outV;
          dst[((size_t)(b * NH + hh) * SEQ + s) * HD_ + d] = f2bf(v);
        }
      }
    }
  }
}

// ---------------------------------------------------------------- grouping
// routes[s][0] == stable-argsort leader of the equal-Cantor-coord class.
// Verify exact row equality vs leader; mismatch -> singleton group.

__global__ void k_init(int* __restrict__ tileQ, int* __restrict__ cnt,
                       int* __restrict__ pos, int* __restrict__ nTiles) {
  const int i = blockIdx.x * 256 + threadIdx.x;   // 0..65535
  tileQ[i] = -1;
  if (i < 4096) { cnt[i] = 0; pos[i] = 0; }
  if (i == 0) *nTiles = 0;
}

__global__ void k_gid(const int* __restrict__ routes, int* __restrict__ gid, int* __restrict__ cnt) {
  const int s = blockIdx.x * 256 + threadIdx.x;
  const int lead = routes[s * 64];
  int g = s;
  if (lead >= 0 && lead < SEQ && lead != s) {
    bool eq = true;
    const int4* a = reinterpret_cast<const int4*>(routes + (size_t)s * 64);
    const int4* b = reinterpret_cast<const int4*>(routes + (size_t)lead * 64);
#pragma unroll
    for (int i = 0; i < 16; ++i) {
      int4 x = a[i], y = b[i];
      eq = eq && (x.x == y.x) && (x.y == y.y) && (x.z == y.z) && (x.w == y.w);
    }
    if (eq) g = lead;
  }
  gid[s] = g;
  atomicAdd(&cnt[g], 1);
}

__global__ void k_tilebase(const int* __restrict__ cnt, int* __restrict__ tileBase,
                           int* __restrict__ nTiles) {
  const int g = blockIdx.x * 256 + threadIdx.x;
  const int c = cnt[g];
  if (c > 0) {
    tileBase[g] = atomicAdd(nTiles, (c + 15) >> 4);
  }
}

__global__ void k_scatter(const int* __restrict__ gid, const int* __restrict__ tileBase,
                          int* __restrict__ pos, int* __restrict__ tileQ,
                          int* __restrict__ tileLead) {
  const int s = blockIdx.x * 256 + threadIdx.x;
  const int g = gid[s];
  const int p = atomicAdd(&pos[g], 1);
  const int tile = tileBase[g] + (p >> 4);
  tileQ[tile * 16 + (p & 15)] = s;
  if ((p & 15) == 0) tileLead[tile] = g;
}

// ---------------------------------------------------------------- grouped MFMA attention
// XCD-affinity layout: grid (8, 64); linear bid = x + y*8, consecutive bids round-robin
// XCDs -> all blocks with the same x land on XCD x. Wave w of block x owns bh = x*4 + w
// for ALL its tiles -> that bh's 1 MB K+V slice stays L2-resident (4 MB/XCD).
// Per task: issue Q(2)->reg, K(8)->LDS, V(8)->LDS; vmcnt(8); QK^T + softmax;
// vmcnt(0)+lgkm; PV.
// K layout rot8:  elem(k,d) at k*64 + ((d + 8*(k&7)) & 63)
// V layout rot16: elem(k,d) at k*64 + ((d + 16*((k>>3)&3)) & 63)

__global__ __launch_bounds__(256)
void k_attn_grp(const unsigned short* __restrict__ Q,
                const unsigned short* __restrict__ Kb,
                const unsigned short* __restrict__ Vb,
                const int* __restrict__ routes,
                const int* __restrict__ tileQ,
                const int* __restrict__ tileLead,
                const int* __restrict__ nTilesPtr,
                unsigned short* __restrict__ att) {
  const int nT = *nTilesPtr;

  __shared__ int sMemRaw[16];
  __shared__ int sMemEff[16];
  __shared__ int sRoutes[64];
  __shared__ alignas(16) unsigned short sK[4][4096];    // 32 KB
  __shared__ alignas(16) unsigned short sV[4][4096];    // 32 KB
  __shared__ alignas(16) unsigned short sP[4][16 * 72]; // 9216 B

  const int tid = threadIdx.x;
  const int wave = tid >> 6, lane = tid & 63;
  unsigned short* KL = sK[wave];
  unsigned short* VL = sV[wave];
  unsigned short* P = sP[wave];
  const int hi = lane >> 4;    // 0..3
  const int l15 = lane & 15;
  const int l7 = lane & 7;
  const int rr = lane >> 3;    // 0..7 (staging row-in-iter)

  const int bh = blockIdx.x * 4 + wave;      // fixed per wave -> L2 reuse
  const size_t base = (size_t)bh * (SEQ * HD_);
  const int b = bh >> 4, h = bh & 15;

  for (int tile = blockIdx.y; tile < nT; tile += gridDim.y) {
    __syncthreads();  // prior iteration's sMem/sRoutes reads complete
    if (tid < 16) {
      const int v = tileQ[tile * 16 + tid];
      const int v0 = tileQ[tile * 16];
      sMemRaw[tid] = v;
      sMemEff[tid] = (v < 0) ? v0 : v;
    } else if (tid >= 64 && tid < 128) {
      const int lead = tileLead[tile];
      sRoutes[tid - 64] = routes[(size_t)lead * 64 + (tid - 64)];
    }
    __syncthreads();

    // ---- Q fragments (global->reg; issued before stages so vmcnt(8) covers them)
    bf16x8 qa0, qa1;
    {
      const unsigned short* qrow = Q + base + (size_t)sMemEff[l15] * HD_ + hi * 8;
      qa0 = *reinterpret_cast<const bf16x8*>(qrow);
      qa1 = *reinterpret_cast<const bf16x8*>(qrow + 32);
    }

    // ---- stage K (rot8): src chunk = (c' - (k&7)) & 7, k&7 == rr
    {
      const int sc = ((l7 - rr) & 7) * 8;
#pragma unroll
      for (int t = 0; t < 8; ++t) {
        const int rk = sRoutes[t * 8 + rr];
        load16_lds(Kb + base + (size_t)rk * HD_ + sc, &KL[t * 512]);
      }
    }
    // ---- stage V (rot16) immediately (separate buffer; overlaps QK/softmax)
    {
#pragma unroll
      for (int t = 0; t < 8; ++t) {
        const int rk = sRoutes[t * 8 + rr];
        const int sc = ((l7 - 2 * (t & 3)) & 7) * 8;
        load16_lds(Vb + base + (size_t)rk * HD_ + sc, &VL[t * 512]);
      }
    }

    // K (and Q) ready; V's 8 newest may still be in flight
    asm volatile("s_waitcnt vmcnt(8)" ::: "memory");
    __builtin_amdgcn_sched_barrier(0);

    // ---- QK^T
    f32x4 accS[4] = {};
    __builtin_amdgcn_s_setprio(1);
#pragma unroll
    for (int nb = 0; nb < 4; ++nb) {
      const int key = nb * 16 + l15;
      const int rot = 8 * (key & 7);
      const int ae0 = key * 64 + (((hi * 8) + rot) & 63);
      const int ae1 = key * 64 + (((32 + hi * 8) + rot) & 63);
      bf16x8 kf0 = *reinterpret_cast<const bf16x8*>(&KL[ae0]);
      bf16x8 kf1 = *reinterpret_cast<const bf16x8*>(&KL[ae1]);
      accS[nb] = __builtin_amdgcn_mfma_f32_16x16x32_bf16(qa0, kf0, accS[nb], 0, 0, 0);
      accS[nb] = __builtin_amdgcn_mfma_f32_16x16x32_bf16(qa1, kf1, accS[nb], 0, 0, 0);
    }
    __builtin_amdgcn_s_setprio(0);

    // ---- softmax per row (row r = 4*hi + jj lives in 16-lane group hi)
#pragma unroll
    for (int jj = 0; jj < 4; ++jj) {
      float m = fmaxf(fmaxf(accS[0][jj], accS[1][jj]), fmaxf(accS[2][jj], accS[3][jj]));
#pragma unroll
      for (int o = 1; o < 16; o <<= 1) m = fmaxf(m, __shfl_xor(m, o));
      const float e0 = __expf((accS[0][jj] - m) * SCALE_);
      const float e1 = __expf((accS[1][jj] - m) * SCALE_);
      const float e2 = __expf((accS[2][jj] - m) * SCALE_);
      const float e3 = __expf((accS[3][jj] - m) * SCALE_);
      float sum = (e0 + e1) + (e2 + e3);
#pragma unroll
      for (int o = 1; o < 16; o <<= 1) sum += __shfl_xor(sum, o);
      const float rs = __builtin_amdgcn_rcpf(sum);
      const int row = hi * 4 + jj;
      P[row * 72 + 0 + l15] = f2bf(e0 * rs);
      P[row * 72 + 16 + l15] = f2bf(e1 * rs);
      P[row * 72 + 32 + l15] = f2bf(e2 * rs);
      P[row * 72 + 48 + l15] = f2bf(e3 * rs);
    }

    // V resident + P writes visible
    asm volatile("s_waitcnt vmcnt(0) lgkmcnt(0)" ::: "memory");
    __builtin_amdgcn_sched_barrier(0);

    // ---- PV: A = P (rows=q, k=key), B-frag = V[k][d] scalar column reads (2-way banks)
    f32x4 accO[4] = {};
#pragma unroll
    for (int ks = 0; ks < 2; ++ks) {
      bf16x8 pf = *reinterpret_cast<const bf16x8*>(&P[l15 * 72 + ks * 32 + hi * 8]);
#pragma unroll
      for (int nb = 0; nb < 4; ++nb) {
        const int d = nb * 16 + l15;
        const int rot = (d + 16 * hi) & 63;  // (k>>3)&3 == hi for k = ks*32+hi*8+j
        bf16x8 vf;
#pragma unroll
        for (int j = 0; j < 8; ++j) {
          const int k = ks * 32 + hi * 8 + j;
          vf[j] = *reinterpret_cast<const __bf16*>(&VL[k * 64 + rot]);
        }
        __builtin_amdgcn_s_setprio(1);
        accO[nb] = __builtin_amdgcn_mfma_f32_16x16x32_bf16(pf, vf, accO[nb], 0, 0, 0);
        __builtin_amdgcn_s_setprio(0);
      }
    }

    // ---- epilogue: att[b][s][h*64 + d]
#pragma unroll
    for (int jj = 0; jj < 4; ++jj) {
      const int sQ = sMemRaw[hi * 4 + jj];
      if (sQ >= 0) {
#pragma unroll
        for (int nb = 0; nb < 4; ++nb) {
          att[((size_t)(b * SEQ + sQ)) * DIM_ + h * HD_ + nb * 16 + l15] = f2bf(accO[nb][jj]);
        }
      }
    }
  }
}

// ---------------------------------------------------------------- launch

extern "C" void kernel_launch(void* const* d_in, const int* in_sizes, int n_in,
                              void* d_out, int out_size, void* d_ws, size_t ws_size,
                              hipStream_t stream) {
  (void)in_sizes; (void)n_in; (void)out_size; (void)ws_size;
  const float* x      = (const float*)d_in[0];
  const float* Wqkv   = (const float*)d_in[1];
  const float* bqkv   = (const float*)d_in[2];
  const float* Wout   = (const float*)d_in[3];
  const float* bout   = (const float*)d_in[4];
  const int*   routes = (const int*)d_in[5];
  float* out = (float*)d_out;

  uint8_t* ws = (uint8_t*)d_ws;
  unsigned short* wqkvT = (unsigned short*)(ws);              //  6,291,456 B (3072x1024 bf16)
  unsigned short* woutT = (unsigned short*)(ws + 6291456);    //  2,097,152 B (1024x1024 bf16)
  unsigned short* Qb    = (unsigned short*)(ws + 8388608);    // 16 MiB
  unsigned short* Kb    = (unsigned short*)(ws + 25165824);   // 16 MiB
  unsigned short* Vb    = (unsigned short*)(ws + 41943040);   // 16 MiB
  unsigned short* att   = (unsigned short*)(ws + 58720256);   // 16 MiB (end 75,497,472)

  // d_out (32 MiB f32): first 16 MiB = xb (dead after GEMM1); second half holds group
  // metadata (dead before GEMM2's output store touches it).
  unsigned short* xb = (unsigned short*)d_out;
  uint8_t* g0 = (uint8_t*)d_out + (16u << 20);
  int* gidArr   = (int*)(g0);                 // 16 KB
  int* cnt      = (int*)(g0 + 16384);         // 16 KB
  int* pos      = (int*)(g0 + 32768);         // 16 KB
  int* tileBase = (int*)(g0 + 49152);         // 16 KB
  int* nTiles   = (int*)(g0 + 65536);         // 4 B
  int* tileLead = (int*)(g0 + 81920);         // 16 KB
  int* tileQ    = (int*)(g0 + 98304);         // 256 KB

  k_init<<<256, 256, 0, stream>>>(tileQ, cnt, pos, nTiles);
  k_gid<<<16, 256, 0, stream>>>(routes, gidArr, cnt);
  k_tilebase<<<16, 256, 0, stream>>>(cnt, tileBase, nTiles);
  k_scatter<<<16, 256, 0, stream>>>(gidArr, tileBase, pos, tileQ, tileLead);

  k_cvt_bf16<<<8192, 256, 0, stream>>>(x, xb);
  k_transpose_cvt<<<dim3(48, 16), 256, 0, stream>>>(Wqkv, wqkvT, 1024, 3072);
  k_transpose_cvt<<<dim3(16, 16), 256, 0, stream>>>(Wout, woutT, 1024, 1024);

  k_gemm_bt<1><<<dim3(64, 24), 256, 0, stream>>>(xb, wqkvT, bqkv, nullptr, Qb, Kb, Vb,
                                                 8192, 3072, 1024);
  k_attn_grp<<<dim3(8, 64), 256, 0, stream>>>(Qb, Kb, Vb, routes, tileQ, tileLead,
                                              nTiles, att);
  k_gemm_bt<0><<<dim3(64, 8), 256, 0, stream>>>(att, woutT, bout, out,
                                                nullptr, nullptr, nullptr, 8192, 1024, 1024);
}

// Round 12
// 154.710 us; speedup vs baseline: 1.4726x; 1.4726x over previous
//
#include <hip/hip_runtime.h>
#include <hip/hip_bf16.h>
#include <stdint.h>

#define DEVI __device__ __forceinline__

typedef __bf16 bf16x8 __attribute__((ext_vector_type(8)));
typedef float f32x4 __attribute__((ext_vector_type(4)));
typedef unsigned short ushort8v __attribute__((ext_vector_type(8)));

static constexpr int SEQ = 4096;
static constexpr int DIM_ = 1024;
static constexpr int NH = 16;
static constexpr int HD_ = 64;
static constexpr float SCALE_ = 0.125f;  // 1/sqrt(64)

DEVI unsigned short f2bf(float f) {
  __hip_bfloat16 h = __float2bfloat16(f);
  return __builtin_bit_cast(unsigned short, h);
}

// ---------------------------------------------------------------- conversions

__global__ void k_cvt_bf16(const float* __restrict__ in, unsigned short* __restrict__ out) {
  int i = (blockIdx.x * 256 + threadIdx.x) * 4;
  float4 v = *reinterpret_cast<const float4*>(in + i);
  ushort4 o;
  o.x = f2bf(v.x); o.y = f2bf(v.y); o.z = f2bf(v.z); o.w = f2bf(v.w);
  *reinterpret_cast<ushort4*>(out + i) = o;
}

// in: K x N f32 (row-major), out: N x K bf16 (row-major)
__global__ void k_transpose_cvt(const float* __restrict__ in, unsigned short* __restrict__ out,
                                int K, int N) {
  __shared__ float tile[64][65];
  const int n0 = blockIdx.x * 64, k0 = blockIdx.y * 64;
  const int tr = threadIdx.x >> 6, tc = threadIdx.x & 63;
#pragma unroll
  for (int p = 0; p < 16; ++p) {
    int r = p * 4 + tr;
    tile[r][tc] = in[(size_t)(k0 + r) * N + n0 + tc];
  }
  __syncthreads();
#pragma unroll
  for (int p = 0; p < 16; ++p) {
    int r = p * 4 + tr;  // output row (n index)
    out[(size_t)(n0 + r) * K + k0 + tc] = f2bf(tile[tc][r]);
  }
}

// ---------------------------------------------------------------- GEMM (A: MxK bf16, Bt: NxK bf16)
// r10 plateau version (best measured: 70.2us gemm<1>). 128x128/BK=32, 2-phase
// double-buffer (stage t+1 BEFORE compute t; ONE barrier per K-tile), T2 chunk-XOR LDS
// swizzle (conflicts ~0), NATURAL block order (r8: XCD remap tripled FETCH). Five
// structural variants (2-barrier, ring-4, 8-phase, 2-phase, B-in-reg) all plateau or
// regress vs this — do not touch without the exact m201 interleave + 256-divisible grid.
// MODE 0: outF[row*N+col] = acc + bias[col]  (f32)
// MODE 1: qkv scatter -> outQ/outK/outV bf16, layout [b][h][s][d]

DEVI void load16_lds(const void* g, void* l) {
  __builtin_amdgcn_global_load_lds((__attribute__((address_space(1))) void*)(g),
                                   (__attribute__((address_space(3))) void*)(l),
                                   16, 0, 0);
}

template <int MODE>
__global__ __launch_bounds__(256, 4)
void k_gemm_bt(const unsigned short* __restrict__ A,
               const unsigned short* __restrict__ Bt,
               const float* __restrict__ bias,
               float* __restrict__ outF,
               unsigned short* __restrict__ outQ,
               unsigned short* __restrict__ outK,
               unsigned short* __restrict__ outV,
               int M, int N, int K) {
  constexpr int BK = 32;
  __shared__ alignas(16) unsigned short As[2][128 * BK];
  __shared__ alignas(16) unsigned short Bs[2][128 * BK];
  const int tid = threadIdx.x;
  const int wave = tid >> 6, lane = tid & 63;
  const int wr = wave >> 1, wc = wave & 1;
  const int l15 = lane & 15, q = lane >> 4;
  const int bm = blockIdx.x * 128, bn = blockIdx.y * 128;

  f32x4 acc[4][4] = {};

  // staging: lane -> slot row = lane>>2, slot chunk = lane&3;
  // logical chunk = (lane&3)^((lane>>3)&3)  (T2 swizzle via pre-swizzled global src)
  const int srow = lane >> 2;
  const int scol = ((lane & 3) ^ ((lane >> 3) & 3)) * 8;
  const unsigned short* aS0 = A + (size_t)(bm + wave * 16 + srow) * K + scol;
  const unsigned short* aS1 = aS0 + (size_t)64 * K;
  const unsigned short* bS0 = Bt + (size_t)(bn + wave * 16 + srow) * K + scol;
  const unsigned short* bS1 = bS0 + (size_t)64 * K;
  const int dOff = (wave * 16) * BK;

  // read side: logical chunk q stored at slot q^((l15>>1)&3)
  const int x3 = (l15 >> 1) & 3;
  const int aRdOff = (wr * 64 + l15) * BK + (q ^ x3) * 8;
  const int bRdOff = (wc * 64 + l15) * BK + (q ^ x3) * 8;

  // prologue: stage tile 0 into buf 0
  load16_lds(aS0, &As[0][dOff]);
  load16_lds(aS1, &As[0][dOff + 64 * BK]);
  load16_lds(bS0, &Bs[0][dOff]);
  load16_lds(bS1, &Bs[0][dOff + 64 * BK]);
  __syncthreads();

  const int NT = K / BK;
#pragma unroll 1
  for (int t = 0; t < NT; ++t) {
    const int cur = t & 1;
    if (t + 1 < NT) {
      const int k1 = (t + 1) * BK;
      const int nxt = cur ^ 1;
      load16_lds(aS0 + k1, &As[nxt][dOff]);
      load16_lds(aS1 + k1, &As[nxt][dOff + 64 * BK]);
      load16_lds(bS0 + k1, &Bs[nxt][dOff]);
      load16_lds(bS1 + k1, &Bs[nxt][dOff + 64 * BK]);
    }

    bf16x8 af[4], bfr[4];
#pragma unroll
    for (int m = 0; m < 4; ++m)
      af[m] = *reinterpret_cast<const bf16x8*>(&As[cur][aRdOff + m * 16 * BK]);
#pragma unroll
    for (int n = 0; n < 4; ++n)
      bfr[n] = *reinterpret_cast<const bf16x8*>(&Bs[cur][bRdOff + n * 16 * BK]);
#pragma unroll
    for (int m = 0; m < 4; ++m)
#pragma unroll
      for (int n = 0; n < 4; ++n)
        acc[m][n] = __builtin_amdgcn_mfma_f32_16x16x32_bf16(af[m], bfr[n], acc[m][n], 0, 0, 0);

    __syncthreads();  // one drain+barrier per K-tile
  }

  // epilogue: D frag (16x16) mapping col = lane&15, row = (lane>>4)*4 + j
  const int r0 = q * 4;
#pragma unroll
  for (int m = 0; m < 4; ++m) {
#pragma unroll
    for (int n = 0; n < 4; ++n) {
      const int col = bn + wc * 64 + n * 16 + l15;
      const float bv = bias[col];
#pragma unroll
      for (int j = 0; j < 4; ++j) {
        const int row = bm + wr * 64 + m * 16 + r0 + j;
        const float v = acc[m][n][j] + bv;
        if constexpr (MODE == 0) {
          outF[(size_t)row * N + col] = v;
        } else {
          const int t = col >> 10;          // 0:Q 1:K 2:V
          const int hh = (col >> 6) & 15;   // head
          const int d = col & 63;
          const int b = row >> 12;
          const int s = row & 4095;
          unsigned short* dst = (t == 0) ? outQ : (t == 1) ? outK : outV;
          dst[((size_t)(b * NH + hh) * SEQ + s) * HD_ + d] = f2bf(v);
        }
      }
    }
  }
}

// ---------------------------------------------------------------- grouping
// routes[s][0] == stable-argsort leader of the equal-Cantor-coord class.
// Verify exact row equality vs leader; mismatch -> singleton group.

__global__ void k_init(int* __restrict__ tileQ, int* __restrict__ cnt,
                       int* __restrict__ pos, int* __restrict__ nTiles) {
  const int i = blockIdx.x * 256 + threadIdx.x;   // 0..65535
  tileQ[i] = -1;
  if (i < 4096) { cnt[i] = 0; pos[i] = 0; }
  if (i == 0) *nTiles = 0;
}

__global__ void k_gid(const int* __restrict__ routes, int* __restrict__ gid, int* __restrict__ cnt) {
  const int s = blockIdx.x * 256 + threadIdx.x;
  const int lead = routes[s * 64];
  int g = s;
  if (lead >= 0 && lead < SEQ && lead != s) {
    bool eq = true;
    const int4* a = reinterpret_cast<const int4*>(routes + (size_t)s * 64);
    const int4* b = reinterpret_cast<const int4*>(routes + (size_t)lead * 64);
#pragma unroll
    for (int i = 0; i < 16; ++i) {
      int4 x = a[i], y = b[i];
      eq = eq && (x.x == y.x) && (x.y == y.y) && (x.z == y.z) && (x.w == y.w);
    }
    if (eq) g = lead;
  }
  gid[s] = g;
  atomicAdd(&cnt[g], 1);
}

__global__ void k_tilebase(const int* __restrict__ cnt, int* __restrict__ tileBase,
                           int* __restrict__ nTiles) {
  const int g = blockIdx.x * 256 + threadIdx.x;
  const int c = cnt[g];
  if (c > 0) {
    tileBase[g] = atomicAdd(nTiles, (c + 15) >> 4);
  }
}

__global__ void k_scatter(const int* __restrict__ gid, const int* __restrict__ tileBase,
                          int* __restrict__ pos, int* __restrict__ tileQ,
                          int* __restrict__ tileLead) {
  const int s = blockIdx.x * 256 + threadIdx.x;
  const int g = gid[s];
  const int p = atomicAdd(&pos[g], 1);
  const int tile = tileBase[g] + (p >> 4);
  tileQ[tile * 16 + (p & 15)] = s;
  if ((p & 15) == 0) tileLead[tile] = g;
}

// ---------------------------------------------------------------- grouped MFMA attention
// r11 change: K fragments load DIRECTLY from global into registers (QK's B-frag is a
// native per-lane 16B row-gather: lane(hi,l15) <- K[routes[nb*16+l15]][hi*8..+7]).
// Drops sK (32KB) + 8 ds_read_b128 + rot8 swizzle -> LDS 41.7KB/block -> 3 blocks/CU
// (12 waves/CU, was 8) for latency hiding. V staging (rot16 gload_lds) unchanged.
// XCD affinity: grid (8, 96); XCD = bid%8 = blockIdx.x; wave w of column x owns
// bh = x*4 + w for all its tiles (1 MB K+V slice per bh; 4 bh/XCD = 4 MB = one L2).
// Per task: issue Q(2)->reg, K(8)->reg, V(8)->LDS; vmcnt(8) [Q+K done, V in flight];
// QK^T + softmax; vmcnt(0)+lgkm; PV.
// V layout rot16: elem(k,d) at k*64 + ((d + 16*((k>>3)&3)) & 63)

__global__ __launch_bounds__(256, 3)
void k_attn_grp(const unsigned short* __restrict__ Q,
                const unsigned short* __restrict__ Kb,
                const unsigned short* __restrict__ Vb,
                const int* __restrict__ routes,
                const int* __restrict__ tileQ,
                const int* __restrict__ tileLead,
                const int* __restrict__ nTilesPtr,
                unsigned short* __restrict__ att) {
  const int nT = *nTilesPtr;

  __shared__ int sMemRaw[16];
  __shared__ int sMemEff[16];
  __shared__ int sRoutes[64];
  __shared__ alignas(16) unsigned short sV[4][4096];    // 32 KB
  __shared__ alignas(16) unsigned short sP[4][16 * 72]; // 9216 B

  const int tid = threadIdx.x;
  const int wave = tid >> 6, lane = tid & 63;
  unsigned short* VL = sV[wave];
  unsigned short* P = sP[wave];
  const int hi = lane >> 4;    // 0..3
  const int l15 = lane & 15;
  const int l7 = lane & 7;
  const int rr = lane >> 3;    // 0..7 (staging row-in-iter)

  const int bh = blockIdx.x * 4 + wave;      // fixed per wave -> L2 reuse (B*H = 32)
  const size_t base = (size_t)bh * (SEQ * HD_);
  const int b = bh >> 4, h = bh & 15;

  for (int tile = blockIdx.y; tile < nT; tile += gridDim.y) {
    __syncthreads();  // prior iteration's sMem/sRoutes reads complete
    if (tid < 16) {
      const int v = tileQ[tile * 16 + tid];
      const int v0 = tileQ[tile * 16];
      sMemRaw[tid] = v;
      sMemEff[tid] = (v < 0) ? v0 : v;
    } else if (tid >= 64 && tid < 128) {
      const int lead = tileLead[tile];
      sRoutes[tid - 64] = routes[(size_t)lead * 64 + (tid - 64)];
    }
    __syncthreads();

    // ---- Q fragments (global->reg)
    bf16x8 qa0, qa1;
    {
      const unsigned short* qrow = Q + base + (size_t)sMemEff[l15] * HD_ + hi * 8;
      qa0 = *reinterpret_cast<const bf16x8*>(qrow);
      qa1 = *reinterpret_cast<const bf16x8*>(qrow + 32);
    }

    // ---- K fragments (global->reg, per-lane row gather; no LDS)
    bf16x8 kf0[4], kf1[4];
#pragma unroll
    for (int nb = 0; nb < 4; ++nb) {
      const int rk = sRoutes[nb * 16 + l15];
      const unsigned short* krow = Kb + base + (size_t)rk * HD_ + hi * 8;
      kf0[nb] = *reinterpret_cast<const bf16x8*>(krow);
      kf1[nb] = *reinterpret_cast<const bf16x8*>(krow + 32);
    }

    // ---- stage V (rot16) into LDS (overlaps QK + softmax)
    {
#pragma unroll
      for (int t = 0; t < 8; ++t) {
        const int rk = sRoutes[t * 8 + rr];
        const int sc = ((l7 - 2 * (t & 3)) & 7) * 8;
        load16_lds(Vb + base + (size_t)rk * HD_ + sc, &VL[t * 512]);
      }
    }

    // Q + K ready; V's 8 loads may still be in flight
    asm volatile("s_waitcnt vmcnt(8)" ::: "memory");
    __builtin_amdgcn_sched_barrier(0);

    // ---- QK^T
    f32x4 accS[4] = {};
    __builtin_amdgcn_s_setprio(1);
#pragma unroll
    for (int nb = 0; nb < 4; ++nb) {
      accS[nb] = __builtin_amdgcn_mfma_f32_16x16x32_bf16(qa0, kf0[nb], accS[nb], 0, 0, 0);
      accS[nb] = __builtin_amdgcn_mfma_f32_16x16x32_bf16(qa1, kf1[nb], accS[nb], 0, 0, 0);
    }
    __builtin_amdgcn_s_setprio(0);

    // ---- softmax per row (row r = 4*hi + jj lives in 16-lane group hi)
#pragma unroll
    for (int jj = 0; jj < 4; ++jj) {
      float m = fmaxf(fmaxf(accS[0][jj], accS[1][jj]), fmaxf(accS[2][jj], accS[3][jj]));
#pragma unroll
      for (int o = 1; o < 16; o <<= 1) m = fmaxf(m, __shfl_xor(m, o));
      const float e0 = __expf((accS[0][jj] - m) * SCALE_);
      const float e1 = __expf((accS[1][jj] - m) * SCALE_);
      const float e2 = __expf((accS[2][jj] - m) * SCALE_);
      const float e3 = __expf((accS[3][jj] - m) * SCALE_);
      float sum = (e0 + e1) + (e2 + e3);
#pragma unroll
      for (int o = 1; o < 16; o <<= 1) sum += __shfl_xor(sum, o);
      const float rs = __builtin_amdgcn_rcpf(sum);
      const int row = hi * 4 + jj;
      P[row * 72 + 0 + l15] = f2bf(e0 * rs);
      P[row * 72 + 16 + l15] = f2bf(e1 * rs);
      P[row * 72 + 32 + l15] = f2bf(e2 * rs);
      P[row * 72 + 48 + l15] = f2bf(e3 * rs);
    }

    // V resident + P writes visible (P is wave-private; lgkm suffices)
    asm volatile("s_waitcnt vmcnt(0) lgkmcnt(0)" ::: "memory");
    __builtin_amdgcn_sched_barrier(0);

    // ---- PV: A = P (rows=q, k=key), B-frag = V[k][d] scalar column reads (2-way banks)
    f32x4 accO[4] = {};
#pragma unroll
    for (int ks = 0; ks < 2; ++ks) {
      bf16x8 pf = *reinterpret_cast<const bf16x8*>(&P[l15 * 72 + ks * 32 + hi * 8]);
#pragma unroll
      for (int nb = 0; nb < 4; ++nb) {
        const int d = nb * 16 + l15;
        const int rot = (d + 16 * hi) & 63;  // (k>>3)&3 == hi for k = ks*32+hi*8+j
        bf16x8 vf;
#pragma unroll
        for (int j = 0; j < 8; ++j) {
          const int k = ks * 32 + hi * 8 + j;
          vf[j] = *reinterpret_cast<const __bf16*>(&VL[k * 64 + rot]);
        }
        __builtin_amdgcn_s_setprio(1);
        accO[nb] = __builtin_amdgcn_mfma_f32_16x16x32_bf16(pf, vf, accO[nb], 0, 0, 0);
        __builtin_amdgcn_s_setprio(0);
      }
    }

    // ---- epilogue: att[b][s][h*64 + d]
#pragma unroll
    for (int jj = 0; jj < 4; ++jj) {
      const int sQ = sMemRaw[hi * 4 + jj];
      if (sQ >= 0) {
#pragma unroll
        for (int nb = 0; nb < 4; ++nb) {
          att[((size_t)(b * SEQ + sQ)) * DIM_ + h * HD_ + nb * 16 + l15] = f2bf(accO[nb][jj]);
        }
      }
    }
  }
}

// ---------------------------------------------------------------- launch

extern "C" void kernel_launch(void* const* d_in, const int* in_sizes, int n_in,
                              void* d_out, int out_size, void* d_ws, size_t ws_size,
                              hipStream_t stream) {
  (void)in_sizes; (void)n_in; (void)out_size; (void)ws_size;
  const float* x      = (const float*)d_in[0];
  const float* Wqkv   = (const float*)d_in[1];
  const float* bqkv   = (const float*)d_in[2];
  const float* Wout   = (const float*)d_in[3];
  const float* bout   = (const float*)d_in[4];
  const int*   routes = (const int*)d_in[5];
  float* out = (float*)d_out;

  uint8_t* ws = (uint8_t*)d_ws;
  unsigned short* wqkvT = (unsigned short*)(ws);              //  6,291,456 B (3072x1024 bf16)
  unsigned short* woutT = (unsigned short*)(ws + 6291456);    //  2,097,152 B (1024x1024 bf16)
  unsigned short* Qb    = (unsigned short*)(ws + 8388608);    // 16 MiB
  unsigned short* Kb    = (unsigned short*)(ws + 25165824);   // 16 MiB
  unsigned short* Vb    = (unsigned short*)(ws + 41943040);   // 16 MiB
  unsigned short* att   = (unsigned short*)(ws + 58720256);   // 16 MiB (end 75,497,472)

  // d_out (32 MiB f32): first 16 MiB = xb (dead after GEMM1); second half holds group
  // metadata (dead before GEMM2's output store touches it).
  unsigned short* xb = (unsigned short*)d_out;
  uint8_t* g0 = (uint8_t*)d_out + (16u << 20);
  int* gidArr   = (int*)(g0);                 // 16 KB
  int* cnt      = (int*)(g0 + 16384);         // 16 KB
  int* pos      = (int*)(g0 + 32768);         // 16 KB
  int* tileBase = (int*)(g0 + 49152);         // 16 KB
  int* nTiles   = (int*)(g0 + 65536);         // 4 B
  int* tileLead = (int*)(g0 + 81920);         // 16 KB
  int* tileQ    = (int*)(g0 + 98304);         // 256 KB

  k_init<<<256, 256, 0, stream>>>(tileQ, cnt, pos, nTiles);
  k_gid<<<16, 256, 0, stream>>>(routes, gidArr, cnt);
  k_tilebase<<<16, 256, 0, stream>>>(cnt, tileBase, nTiles);
  k_scatter<<<16, 256, 0, stream>>>(gidArr, tileBase, pos, tileQ, tileLead);

  k_cvt_bf16<<<8192, 256, 0, stream>>>(x, xb);
  k_transpose_cvt<<<dim3(48, 16), 256, 0, stream>>>(Wqkv, wqkvT, 1024, 3072);
  k_transpose_cvt<<<dim3(16, 16), 256, 0, stream>>>(Wout, woutT, 1024, 1024);

  k_gemm_bt<1><<<dim3(64, 24), 256, 0, stream>>>(xb, wqkvT, bqkv, nullptr, Qb, Kb, Vb,
                                                 8192, 3072, 1024);
  k_attn_grp<<<dim3(8, 96), 256, 0, stream>>>(Qb, Kb, Vb, routes, tileQ, tileLead,
                                              nTiles, att);
  k_gemm_bt<0><<<dim3(64, 8), 256, 0, stream>>>(att, woutT, bout, out,
                                                nullptr, nullptr, nullptr, 8192, 1024, 1024);
}